// Round 13
// baseline (7698.362 us; speedup 1.0000x reference)
//
#include <hip/hip_runtime.h>
#include <hip/hip_bf16.h>

typedef __attribute__((ext_vector_type(8))) short bhalf8;
typedef __attribute__((ext_vector_type(4))) float fvec4;
typedef __attribute__((ext_vector_type(4))) unsigned u32x4;

static __device__ __forceinline__ unsigned short f2bf(float f) {
  unsigned u = __builtin_bit_cast(unsigned, f);
  u = (u + 0x7fffu + ((u >> 16) & 1u)) >> 16;   // round-to-nearest-even
  return (unsigned short)u;
}
static __device__ __forceinline__ float tanh_fast(float x) {
  x = fminf(12.f, fmaxf(-12.f, x));
  float e = __expf(2.f * x);
  return (e - 1.f) / (e + 1.f);
}
static __device__ __forceinline__ fvec4 tanh4(fvec4 v) {
  fvec4 r;
  r[0] = tanh_fast(v[0]); r[1] = tanh_fast(v[1]);
  r[2] = tanh_fast(v[2]); r[3] = tanh_fast(v[3]);
  return r;
}
static __device__ __forceinline__ bhalf8 load_w8(const float* p) {
  fvec4 a = *(const fvec4*)p;
  fvec4 b = *(const fvec4*)(p + 4);
  bhalf8 r;
  r[0] = (short)f2bf(a[0]); r[1] = (short)f2bf(a[1]);
  r[2] = (short)f2bf(a[2]); r[3] = (short)f2bf(a[3]);
  r[4] = (short)f2bf(b[0]); r[5] = (short)f2bf(b[1]);
  r[6] = (short)f2bf(b[2]); r[7] = (short)f2bf(b[3]);
  return r;
}

// ---- fabric-coherent (sc0 sc1): the only proven tier (r4/r9/r12). SESSION RULES:
// ---- (1) no asm-load destination window across a GEMM (r6/r8) — glls are immune;
// ---- (2) staging via global_load_lds; (3) flags/polls fused-vmcnt sc0sc1 always.
static __device__ __forceinline__ void st_f32_coh(float* p, float v) {
  asm volatile("global_store_dword %0, %1, off sc0 sc1" :: "v"(p), "v"(v) : "memory");
}
static __device__ __forceinline__ void st_u32_coh(unsigned* p, unsigned v) {
  asm volatile("global_store_dword %0, %1, off sc0 sc1" :: "v"(p), "v"(v) : "memory");
}
static __device__ __forceinline__ void st16_coh(void* p, u32x4 v) {
  asm volatile("global_store_dwordx4 %0, %1, off sc0 sc1" :: "v"(p), "v"(v) : "memory");
}
static __device__ __forceinline__ unsigned ld_u32_coh(const unsigned* p) {
  unsigned v;
  asm volatile("global_load_dword %0, %1, off sc0 sc1\n\ts_waitcnt vmcnt(0)"
               : "=v"(v) : "v"(p) : "memory");
  return v;
}
static __device__ __forceinline__ float ld_f32_coh(const float* p) {
  float v;
  asm volatile("global_load_dword %0, %1, off sc0 sc1\n\ts_waitcnt vmcnt(0)"
               : "=v"(v) : "v"(p) : "memory");
  return v;
}
static __device__ __forceinline__ void gll16_coh(const void* g, void* lds) {
  __builtin_amdgcn_global_load_lds(
      (const __attribute__((address_space(1))) void*)g,
      (__attribute__((address_space(3))) void*)lds, 16, 0, 0x11);
}

#define MFMA16(a, b, c) __builtin_amdgcn_mfma_f32_16x16x32_bf16((a), (b), (c), 0, 0, 0)

#define POLL(base, tgtv)                                                     \
  {                                                                          \
    const unsigned tgt_ = (unsigned)(tgtv);                                  \
    const unsigned* fp_ = (base) + (lane & 15);                              \
    for (;;) {                                                               \
      unsigned v_ = (lane < 16) ? ld_u32_coh(fp_) : tgt_;                    \
      bool ok_ = (lane >= 16) || ((lane & 15) == memb) || (v_ >= tgt_);      \
      if (__all(ok_)) break;                                                 \
      __builtin_amdgcn_s_sleep(1);                                           \
    }                                                                        \
    __builtin_amdgcn_sched_barrier(0);                                       \
  }

// Persistent kernel, 256 WGs x 256 thr, 1 WG/CU -> grid HW-resident, spin safe.
// TWO independent 16-row recurrence chains per WG (A/B), interleaved so each
// chain's exchange round trip flies under the other chain's compute/store phases.
// Per-chain protocol identical to round 12 (proven).
extern "C" __global__ void __launch_bounds__(256, 1)
alarm_rnn_persist(const float* __restrict__ X, const float* __restrict__ Win1,
                  const float* __restrict__ bin1, const float* __restrict__ Wrec1,
                  const float* __restrict__ Win2, const float* __restrict__ bin2,
                  const float* __restrict__ Wrec2, const float* __restrict__ Wout,
                  const float* __restrict__ bout, float* __restrict__ out,
                  unsigned* flags, unsigned short* gbuf0, unsigned short* gbuf1,
                  unsigned short* z2b0, unsigned short* z2b1, float* z1buf)
{
  constexpr int kL = 512, kI = 256, kH = 1024;
  // LDS: zA[0,32K) zB[32K,64K) z2A[64K,96K) z2B[96K,128K) | X: A 2x8K @128K, B 2x8K @144K
  extern __shared__ char smem[];
  char* zA = smem;
  char* zB = smem + 32768;
  char* z2A = smem + 65536;
  char* z2B = smem + 98304;
  char* xA = smem + 131072;
  char* xB = smem + 147456;

  const int tid = threadIdx.x, bid = blockIdx.x;
  const int grp = bid >> 4, memb = bid & 15;
  const int lane = tid & 63, w = tid >> 6;
  const int row16 = lane & 15, kq = lane >> 4;
  const int sw = (row16 & 7) << 4;
  const int hcol = memb * 64 + w * 16 + row16;
  const int rbA = grp * 32, rbB = grp * 32 + 16;
  unsigned* flagsA = flags + grp * 16;
  unsigned* flagsB = flags + 256 + grp * 16;

  // ---- one-time: weights -> registers (B-fragment layout) ----
  bhalf8 w1[32], w2[32], wi1[8], wi2[8];
  {
    const float* p1 = Wrec1 + (size_t)hcol * kH + kq * 8;
    const float* p2 = Wrec2 + (size_t)hcol * kH + kq * 8;
#pragma unroll
    for (int kk = 0; kk < 32; ++kk) {
      w1[kk] = load_w8(p1 + kk * 32);
      w2[kk] = load_w8(p2 + kk * 32);
    }
    const float* q1 = Win1 + (size_t)hcol * kI + kq * 8;
    const float* q2 = Win2 + (size_t)hcol * kI + kq * 8;
#pragma unroll
    for (int kk = 0; kk < 8; ++kk) {
      wi1[kk] = load_w8(q1 + kk * 32);
      wi2[kk] = load_w8(q2 + kk * 32);
    }
  }
  const float bv1 = bin1[hcol];
  const float bv2 = bin2[hcol];
  fvec4 z2cA = {0.f, 0.f, 0.f, 0.f}, z2cB = {0.f, 0.f, 0.f, 0.f};

  // X stage: 16 rows x 256 f32 -> bf16 swizzled LDS (16 thr/row, 16 floats each)
  auto stage_x = [&](int rb, int step, char* dst) {
    int r = tid >> 4, t = tid & 15;
    const float* xp = X + (size_t)(rb + r) * (kL * kI) + (size_t)step * kI;
#pragma unroll
    for (int j = 0; j < 4; ++j) {
      fvec4 v = *(const fvec4*)(xp + t * 4 + j * 64);
      ushort4 pk;
      pk.x = f2bf(v[0]); pk.y = f2bf(v[1]); pk.z = f2bf(v[2]); pk.w = f2bf(v[3]);
      int i0 = t * 4 + j * 64;
      *(ushort4*)(dst + (r << 9) + ((i0 * 2) ^ ((r & 7) << 4))) = pk;
    }
  };
  // z-tile stage: 16 rows x 2KB via 8 glls/thread, source-swizzled, dest linear
  auto stage_z = [&](const unsigned short* src, int rb, char* dst) {
#pragma unroll
    for (int it = 0; it < 8; ++it) {
      int ci = (((it + memb) & 7) * 4) + w;          // 0..31, member-staggered
      int r = ci >> 1, colb = (ci & 1) * 1024 + lane * 16;
      gll16_coh((const char*)src + (((size_t)(rb + r)) << 11) + (colb ^ ((r & 7) << 4)),
                dst + ci * 1024 + lane * 16);
    }
  };

  // ---- prologue: X(0),X(1) both chains; A z12(0)+z2(0) staged ----
  stage_x(rbA, 0, xA); stage_x(rbA, 1, xA + 8192);
  stage_x(rbB, 0, xB); stage_x(rbB, 1, xB + 8192);
  stage_z(gbuf0, rbA, zA);
  stage_z(z2b0, rbA, z2A);
  asm volatile("s_waitcnt vmcnt(0)" ::: "memory");
  __syncthreads();

  for (int l = 0; l < kL; ++l) {
    const bool ev = ((l & 1) == 0);

    // ================= half A: GEMM A(l); stage B(l) =================
    if (l > 0) POLL(flagsB, l);
    {
      stage_z((l & 1) ? gbuf1 : gbuf0, rbB, zB);
      if (ev) stage_z(((l >> 1) & 1) ? z2b1 : z2b0, rbB, z2B);
      __builtin_amdgcn_sched_barrier(0);
    }
    {
      const char* xb = xA + ((l & 1) << 13);
      fvec4 acc = {bv1, bv1, bv1, bv1};
#pragma unroll
      for (int kk = 0; kk < 8; ++kk) {
        int cb = kk * 64 + kq * 16;
        acc = MFMA16(*(const bhalf8*)(xb + (row16 << 9) + (cb ^ sw)), wi1[kk], acc);
      }
      fvec4 c2a = {bv2, bv2, bv2, bv2};
      if (ev) {
#pragma unroll
        for (int kk = 0; kk < 8; ++kk) {
          int cb = kk * 64 + kq * 16;
          c2a = MFMA16(*(const bhalf8*)(xb + (row16 << 9) + (cb ^ sw)), wi2[kk], c2a);
        }
      }
#pragma unroll
      for (int kk = 0; kk < 32; ++kk) {
        int cb = kk * 64 + kq * 16;
        acc = MFMA16(*(const bhalf8*)(zA + (row16 << 11) + (cb ^ sw)), w1[kk], acc);
      }
      fvec4 z1n = tanh4(acc);
      if (ev) {
#pragma unroll
        for (int kk = 0; kk < 32; ++kk) {
          int cb = kk * 64 + kq * 16;
          c2a = MFMA16(*(const bhalf8*)(z2A + (row16 << 11) + (cb ^ sw)), w2[kk], c2a);
        }
        z2cA = tanh4(c2a);
      }
      __syncthreads();  // all waves done reading zA/z2A (B-stage glls untouched regions)
      if (l < kL - 1) {
        const int colb2 = (w * 16 + row16) * 2;
#pragma unroll
        for (int i = 0; i < 4; ++i) {
          int r0 = kq * 4 + i;
          *(unsigned short*)(zA + r0 * 128 + (colb2 ^ ((r0 & 7) << 4))) = f2bf(z1n[i] + z2cA[i]);
          if (ev)
            *(unsigned short*)(zA + 2048 + r0 * 128 + (colb2 ^ ((r0 & 7) << 4))) = f2bf(z2cA[i]);
        }
        __syncthreads();
        if (tid < 128) {
          int r = tid >> 3, s = tid & 7;
          u32x4 v = *(const u32x4*)(zA + r * 128 + ((s * 16) ^ ((r & 7) << 4)));
          unsigned short* dst = (l & 1) ? gbuf0 : gbuf1;
          st16_coh((char*)dst + (((size_t)(rbA + r)) << 11) + memb * 128 + s * 16, v);
          if (ev) {
            u32x4 v2 = *(const u32x4*)(zA + 2048 + r * 128 + ((s * 16) ^ ((r & 7) << 4)));
            unsigned short* z2dst = ((l >> 1) & 1) ? z2b0 : z2b1;
            st16_coh((char*)z2dst + (((size_t)(rbA + r)) << 11) + memb * 128 + s * 16, v2);
          }
        }
      } else {
#pragma unroll
        for (int i = 0; i < 4; ++i)
          st_f32_coh(z1buf + (size_t)(rbA + kq * 4 + i) * kH + hcol, z1n[i]);
      }
      asm volatile("s_waitcnt vmcnt(0)" ::: "memory");  // A stores + B-stage drained
      __syncthreads();
      if (tid == 0) st_u32_coh(flagsA + memb, (unsigned)(l + 1));
      if (l + 2 < kL) stage_x(rbA, l + 2, xA + ((l & 1) << 13));
    }

    // ================= half B: GEMM B(l); stage A(l+1) =================
    if (l + 1 < kL) {
      POLL(flagsA, l + 1);
      stage_z(((l + 1) & 1) ? gbuf1 : gbuf0, rbA, zA);
      if (((l + 1) & 1) == 0) stage_z((((l + 1) >> 1) & 1) ? z2b1 : z2b0, rbA, z2A);
      __builtin_amdgcn_sched_barrier(0);
    }
    {
      const char* xb = xB + ((l & 1) << 13);
      fvec4 acc = {bv1, bv1, bv1, bv1};
#pragma unroll
      for (int kk = 0; kk < 8; ++kk) {
        int cb = kk * 64 + kq * 16;
        acc = MFMA16(*(const bhalf8*)(xb + (row16 << 9) + (cb ^ sw)), wi1[kk], acc);
      }
      fvec4 c2a = {bv2, bv2, bv2, bv2};
      if (ev) {
#pragma unroll
        for (int kk = 0; kk < 8; ++kk) {
          int cb = kk * 64 + kq * 16;
          c2a = MFMA16(*(const bhalf8*)(xb + (row16 << 9) + (cb ^ sw)), wi2[kk], c2a);
        }
      }
#pragma unroll
      for (int kk = 0; kk < 32; ++kk) {
        int cb = kk * 64 + kq * 16;
        acc = MFMA16(*(const bhalf8*)(zB + (row16 << 11) + (cb ^ sw)), w1[kk], acc);
      }
      fvec4 z1n = tanh4(acc);
      if (ev) {
#pragma unroll
        for (int kk = 0; kk < 32; ++kk) {
          int cb = kk * 64 + kq * 16;
          c2a = MFMA16(*(const bhalf8*)(z2B + (row16 << 11) + (cb ^ sw)), w2[kk], c2a);
        }
        z2cB = tanh4(c2a);
      }
      __syncthreads();
      if (l < kL - 1) {
        const int colb2 = (w * 16 + row16) * 2;
#pragma unroll
        for (int i = 0; i < 4; ++i) {
          int r0 = kq * 4 + i;
          *(unsigned short*)(zB + r0 * 128 + (colb2 ^ ((r0 & 7) << 4))) = f2bf(z1n[i] + z2cB[i]);
          if (ev)
            *(unsigned short*)(zB + 2048 + r0 * 128 + (colb2 ^ ((r0 & 7) << 4))) = f2bf(z2cB[i]);
        }
        __syncthreads();
        if (tid < 128) {
          int r = tid >> 3, s = tid & 7;
          u32x4 v = *(const u32x4*)(zB + r * 128 + ((s * 16) ^ ((r & 7) << 4)));
          unsigned short* dst = (l & 1) ? gbuf0 : gbuf1;
          st16_coh((char*)dst + (((size_t)(rbB + r)) << 11) + memb * 128 + s * 16, v);
          if (ev) {
            u32x4 v2 = *(const u32x4*)(zB + 2048 + r * 128 + ((s * 16) ^ ((r & 7) << 4)));
            unsigned short* z2dst = ((l >> 1) & 1) ? z2b0 : z2b1;
            st16_coh((char*)z2dst + (((size_t)(rbB + r)) << 11) + memb * 128 + s * 16, v2);
          }
        }
      } else {
#pragma unroll
        for (int i = 0; i < 4; ++i)
          st_f32_coh(z1buf + (size_t)(rbB + kq * 4 + i) * kH + hcol, z1n[i]);
      }
      asm volatile("s_waitcnt vmcnt(0)" ::: "memory");  // B stores + A-stage drained
      __syncthreads();
      if (tid == 0) st_u32_coh(flagsB + memb, (unsigned)(l + 1));
      if (l + 2 < kL) stage_x(rbB, l + 2, xB + ((l & 1) << 13));
    }
  }

  // ---- epilogue: out[b] = tanh(z1[b,:] . Wout + bout), one WG per group ----
  if (memb == 0) {
    POLL(flagsA, kL);
    POLL(flagsB, kL);
    int r = tid >> 3, q = tid & 7;
    const float* zr = z1buf + (size_t)(grp * 32 + r) * kH;
    float s = 0.f;
    for (int h = q * 128; h < q * 128 + 128; ++h) s += ld_f32_coh(zr + h) * Wout[h];
    s += __shfl_xor(s, 1);
    s += __shfl_xor(s, 2);
    s += __shfl_xor(s, 4);
    if (q == 0) out[grp * 32 + r] = tanh_fast(s + bout[0]);
  }
}

extern "C" void kernel_launch(void* const* d_in, const int* in_sizes, int n_in,
                              void* d_out, int out_size, void* d_ws, size_t ws_size,
                              hipStream_t stream) {
  const float* X = (const float*)d_in[0];
  const float* Win1 = (const float*)d_in[1];
  const float* bin1 = (const float*)d_in[2];
  const float* Wrec1 = (const float*)d_in[3];
  const float* Win2 = (const float*)d_in[4];
  const float* bin2 = (const float*)d_in[5];
  const float* Wrec2 = (const float*)d_in[6];
  const float* Wout = (const float*)d_in[7];
  const float* bout = (const float*)d_in[8];
  float* out = (float*)d_out;

  char* ws = (char*)d_ws;
  unsigned* flags = (unsigned*)ws;                                   // 512 dwords (A|B)
  unsigned short* gbuf0 = (unsigned short*)(ws + 4096);              // 1 MB z12 ping
  unsigned short* gbuf1 = (unsigned short*)(ws + 4096 + (1 << 20));  // 1 MB z12 pong
  unsigned short* z2b0 = (unsigned short*)(ws + 4096 + (2 << 20));   // 1 MB z2 ping
  unsigned short* z2b1 = (unsigned short*)(ws + 4096 + (3 << 20));   // 1 MB z2 pong
  float* z1buf = (float*)(ws + 4096 + (4 << 20));                    // 2 MB final z1 (f32)

  (void)hipMemsetAsync(flags, 0, 4096, stream);
  (void)hipMemsetAsync(gbuf0, 0, (size_t)512 * 1024 * 2, stream);  // z12(l=0) = 0
  (void)hipMemsetAsync(z2b0, 0, (size_t)512 * 1024 * 2, stream);   // z2(l=0)  = 0

  (void)hipFuncSetAttribute((const void*)alarm_rnn_persist,
                            hipFuncAttributeMaxDynamicSharedMemorySize, 163840);

  alarm_rnn_persist<<<dim3(256), dim3(256), 163840, stream>>>(
      X, Win1, bin1, Wrec1, Win2, bin2, Wrec2, Wout, bout, out,
      flags, gbuf0, gbuf1, z2b0, z2b1, z1buf);
}

// Round 14
// 6201.715 us; speedup vs baseline: 1.2413x; 1.2413x over previous
//
#include <hip/hip_runtime.h>
#include <hip/hip_bf16.h>

typedef __attribute__((ext_vector_type(8))) short bhalf8;
typedef __attribute__((ext_vector_type(4))) float fvec4;
typedef __attribute__((ext_vector_type(4))) unsigned u32x4;

static __device__ __forceinline__ unsigned short f2bf(float f) {
  unsigned u = __builtin_bit_cast(unsigned, f);
  u = (u + 0x7fffu + ((u >> 16) & 1u)) >> 16;   // round-to-nearest-even
  return (unsigned short)u;
}
static __device__ __forceinline__ float tanh_fast(float x) {
  x = fminf(12.f, fmaxf(-12.f, x));
  float e = __expf(2.f * x);
  return (e - 1.f) / (e + 1.f);
}
static __device__ __forceinline__ fvec4 tanh4(fvec4 v) {
  fvec4 r;
  r[0] = tanh_fast(v[0]); r[1] = tanh_fast(v[1]);
  r[2] = tanh_fast(v[2]); r[3] = tanh_fast(v[3]);
  return r;
}
static __device__ __forceinline__ bhalf8 load_w8(const float* p) {
  fvec4 a = *(const fvec4*)p;
  fvec4 b = *(const fvec4*)(p + 4);
  bhalf8 r;
  r[0] = (short)f2bf(a[0]); r[1] = (short)f2bf(a[1]);
  r[2] = (short)f2bf(a[2]); r[3] = (short)f2bf(a[3]);
  r[4] = (short)f2bf(b[0]); r[5] = (short)f2bf(b[1]);
  r[6] = (short)f2bf(b[2]); r[7] = (short)f2bf(b[3]);
  return r;
}

// ---- fabric-coherent (sc0 sc1): the only proven tier (r4/r9/r12). SESSION RULES:
// ---- (1) no asm-load destination window across a GEMM (r6/r8) — glls are immune;
// ---- (2) staging via global_load_lds; (3) flags/polls fused-vmcnt sc0sc1 always;
// ---- (4) one poll/drain/flag set per step — phase-splitting doubles overhead (r13).
static __device__ __forceinline__ void st_f32_coh(float* p, float v) {
  asm volatile("global_store_dword %0, %1, off sc0 sc1" :: "v"(p), "v"(v) : "memory");
}
static __device__ __forceinline__ void st_u32_coh(unsigned* p, unsigned v) {
  asm volatile("global_store_dword %0, %1, off sc0 sc1" :: "v"(p), "v"(v) : "memory");
}
static __device__ __forceinline__ void st16_coh(void* p, u32x4 v) {
  asm volatile("global_store_dwordx4 %0, %1, off sc0 sc1" :: "v"(p), "v"(v) : "memory");
}
static __device__ __forceinline__ unsigned ld_u32_coh(const unsigned* p) {
  unsigned v;
  asm volatile("global_load_dword %0, %1, off sc0 sc1\n\ts_waitcnt vmcnt(0)"
               : "=v"(v) : "v"(p) : "memory");
  return v;
}
static __device__ __forceinline__ float ld_f32_coh(const float* p) {
  float v;
  asm volatile("global_load_dword %0, %1, off sc0 sc1\n\ts_waitcnt vmcnt(0)"
               : "=v"(v) : "v"(p) : "memory");
  return v;
}
static __device__ __forceinline__ void gll16_coh(const void* g, void* lds) {
  __builtin_amdgcn_global_load_lds(
      (const __attribute__((address_space(1))) void*)g,
      (__attribute__((address_space(3))) void*)lds, 16, 0, 0x11);
}

#define MFMA16(a, b, c) __builtin_amdgcn_mfma_f32_16x16x32_bf16((a), (b), (c), 0, 0, 0)

// Persistent kernel, 256 WGs x 256 thr, 1 WG/CU -> grid HW-resident, spin safe.
// WG=(grp: 32 batch rows, memb: 64 H-cols). Round-12 structure (best: 5.48 ms) plus:
// z2 staging moved from even-step A1 to ODD-step post-flag slack. Legal because
// z2[e] (stored during even step 2e, covered by flag(2e+1)) is globally visible to
// any WG already inside step 2e+1 — the slack glls fly through the poll + next
// even step's A1/A2 and are drained by its existing A3 vmcnt(0).
extern "C" __global__ void __launch_bounds__(256, 1)
alarm_rnn_persist(const float* __restrict__ X, const float* __restrict__ Win1,
                  const float* __restrict__ bin1, const float* __restrict__ Wrec1,
                  const float* __restrict__ Win2, const float* __restrict__ bin2,
                  const float* __restrict__ Wrec2, const float* __restrict__ Wout,
                  const float* __restrict__ bout, float* __restrict__ out,
                  unsigned* flags, unsigned short* gbuf0, unsigned short* gbuf1,
                  unsigned short* z2b0, unsigned short* z2b1, float* z1buf)
{
  constexpr int kL = 512, kI = 256, kH = 1024;
  // LDS: [0,64K) z12 (also [0,8K) store-transpose) | [64K,128K) z2
  //      | [128K,160K) X ping-pong (2 x 16K)
  extern __shared__ char smem[];

  const int tid = threadIdx.x, bid = blockIdx.x;
  const int grp = bid >> 4, memb = bid & 15;
  const int lane = tid & 63, w = tid >> 6;
  const int row16 = lane & 15, kq = lane >> 4;
  const int sw = (row16 & 7) << 4;
  const int hcol = memb * 64 + w * 16 + row16;
  const int brow0 = grp * 32;

  // ---- one-time: weights -> registers (B-fragment: lane holds W[hcol, kq*8+j (+32*kk)]) ----
  bhalf8 w1[32], w2[32], wi1[8], wi2[8];
  {
    const float* p1 = Wrec1 + (size_t)hcol * kH + kq * 8;
    const float* p2 = Wrec2 + (size_t)hcol * kH + kq * 8;
#pragma unroll
    for (int kk = 0; kk < 32; ++kk) {
      w1[kk] = load_w8(p1 + kk * 32);
      w2[kk] = load_w8(p2 + kk * 32);
    }
    const float* q1 = Win1 + (size_t)hcol * kI + kq * 8;
    const float* q2 = Win2 + (size_t)hcol * kI + kq * 8;
#pragma unroll
    for (int kk = 0; kk < 8; ++kk) {
      wi1[kk] = load_w8(q1 + kk * 32);
      wi2[kk] = load_w8(q2 + kk * 32);
    }
  }
  const float bv1 = bin1[hcol];
  const float bv2 = bin2[hcol];
  fvec4 z2c0 = {0.f, 0.f, 0.f, 0.f}, z2c1 = {0.f, 0.f, 0.f, 0.f};

  // z2 tile stage via glls (source-swizzled, dest linear), member-staggered
  auto stage_z2 = [&](const unsigned short* src) {
#pragma unroll
    for (int it = 0; it < 16; ++it) {
      int itx = (it + memb) & 15;
      int c = ((itx * 4 + w) << 6) + lane;
      int r = c >> 7, cbs = (c & 127) * 16;
      gll16_coh((const char*)src + (((size_t)(brow0 + r)) << 11) + (cbs ^ ((r & 7) << 4)),
                smem + 65536 + ((itx * 4 + w) << 10));
    }
  };

  // ---- prologue: stage X(0), X(1); stage z2(l=0) source (memset z2b0) ----
  {
    int r = tid >> 3, q = tid & 7;
#pragma unroll
    for (int p = 0; p < 2; ++p) {
      const float* xp = X + (size_t)(brow0 + r) * (kL * kI) + (size_t)p * kI;
      fvec4 xv[8];
#pragma unroll
      for (int j = 0; j < 8; ++j) xv[j] = *(const fvec4*)(xp + q * 4 + j * 32);
#pragma unroll
      for (int j = 0; j < 8; ++j) {
        int i0 = q * 4 + j * 32;
        ushort4 pk;
        pk.x = f2bf(xv[j][0]); pk.y = f2bf(xv[j][1]);
        pk.z = f2bf(xv[j][2]); pk.w = f2bf(xv[j][3]);
        *(ushort4*)(smem + 131072 + p * 16384 + (r << 9) + ((i0 * 2) ^ ((r & 7) << 4))) = pk;
      }
    }
  }
  stage_z2(z2b0);
  asm volatile("s_waitcnt vmcnt(0)" ::: "memory");
  __syncthreads();

  for (int l = 0; l < kL; ++l) {
    const bool even = ((l & 1) == 0);
    const int e = l >> 1;

    // ---- A1: issue z12 global->LDS (z2 already staged/in-flight from odd slack) ----
    {
      const unsigned short* zsrc = (l & 1) ? gbuf1 : gbuf0;
#pragma unroll
      for (int it = 0; it < 16; ++it) {
        int itx = (it + memb) & 15;                  // stagger start across members
        int c = ((itx * 4 + w) << 6) + lane;
        int r = c >> 7, cbs = (c & 127) * 16;
        gll16_coh((const char*)zsrc + (((size_t)(brow0 + r)) << 11) + (cbs ^ ((r & 7) << 4)),
                  smem + ((itx * 4 + w) << 10));
      }
      __builtin_amdgcn_sched_barrier(0);  // keep issues above the MFMA shadow
    }

    // ---- A2: Win1*X(l) (+ Win2*X(l) on even) under the load shadow ----
    const char* xb = smem + 131072 + ((l & 1) << 14);
    fvec4 acc0 = {bv1, bv1, bv1, bv1}, acc1 = acc0;
#pragma unroll
    for (int kk = 0; kk < 8; ++kk) {
      int cb = kk * 64 + kq * 16;
      bhalf8 a0 = *(const bhalf8*)(xb + (row16 << 9) + (cb ^ sw));
      bhalf8 a1 = *(const bhalf8*)(xb + ((16 + row16) << 9) + (cb ^ sw));
      acc0 = MFMA16(a0, wi1[kk], acc0);
      acc1 = MFMA16(a1, wi1[kk], acc1);
    }
    fvec4 c2a0 = {bv2, bv2, bv2, bv2}, c2a1 = c2a0;
    if (even) {
#pragma unroll
      for (int kk = 0; kk < 8; ++kk) {
        int cb = kk * 64 + kq * 16;
        bhalf8 a0 = *(const bhalf8*)(xb + (row16 << 9) + (cb ^ sw));
        bhalf8 a1 = *(const bhalf8*)(xb + ((16 + row16) << 9) + (cb ^ sw));
        c2a0 = MFMA16(a0, wi2[kk], c2a0);
        c2a1 = MFMA16(a1, wi2[kk], c2a1);
      }
    }
    // ---- A3: all staged data (z12 + slack z2) complete -> visible to all waves ----
    asm volatile("s_waitcnt vmcnt(0)" ::: "memory");
    __builtin_amdgcn_sched_barrier(0);
    __syncthreads();  // #1

    // ---- B1: z1 = tanh(acc + Wrec1 * z12) ----
#pragma unroll
    for (int kk = 0; kk < 32; ++kk) {
      int cb = kk * 64 + kq * 16;
      bhalf8 a0 = *(const bhalf8*)(smem + (row16 << 11) + (cb ^ sw));
      bhalf8 a1 = *(const bhalf8*)(smem + ((16 + row16) << 11) + (cb ^ sw));
      acc0 = MFMA16(a0, w1[kk], acc0);
      acc1 = MFMA16(a1, w1[kk], acc1);
    }
    fvec4 z1n0 = tanh4(acc0), z1n1 = tanh4(acc1);

    // ---- B2 (even): z2 = tanh(c2a + Wrec2 * z2prev) ----
    if (even) {
#pragma unroll
      for (int kk = 0; kk < 32; ++kk) {
        int cb = kk * 64 + kq * 16;
        bhalf8 a0 = *(const bhalf8*)(smem + 65536 + (row16 << 11) + (cb ^ sw));
        bhalf8 a1 = *(const bhalf8*)(smem + 65536 + ((16 + row16) << 11) + (cb ^ sw));
        c2a0 = MFMA16(a0, w2[kk], c2a0);
        c2a1 = MFMA16(a1, w2[kk], c2a1);
      }
      z2c0 = tanh4(c2a0);
      z2c1 = tanh4(c2a1);
    }

    // ---- C: coalesced publish via LDS transpose (values bit-identical to r12) ----
    __syncthreads();  // #1.5: all GEMM reads of z12/z2 LDS regions complete
    if (l < kL - 1) {
      const int colb = (w * 16 + row16) * 2;  // byte col within this WG's 64-col tile
#pragma unroll
      for (int i = 0; i < 4; ++i) {
        int r0 = kq * 4 + i, r1 = 16 + kq * 4 + i;
        *(unsigned short*)(smem + r0 * 128 + (colb ^ ((r0 & 7) << 4))) = f2bf(z1n0[i] + z2c0[i]);
        *(unsigned short*)(smem + r1 * 128 + (colb ^ ((r1 & 7) << 4))) = f2bf(z1n1[i] + z2c1[i]);
      }
      if (even) {
#pragma unroll
        for (int i = 0; i < 4; ++i) {
          int r0 = kq * 4 + i, r1 = 16 + kq * 4 + i;
          *(unsigned short*)(smem + 4096 + r0 * 128 + (colb ^ ((r0 & 7) << 4))) = f2bf(z2c0[i]);
          *(unsigned short*)(smem + 4096 + r1 * 128 + (colb ^ ((r1 & 7) << 4))) = f2bf(z2c1[i]);
        }
      }
      __syncthreads();  // #1.75: transpose tiles complete
      {
        int r = tid >> 3, s = tid & 7;
        u32x4 v = *(const u32x4*)(smem + r * 128 + ((s * 16) ^ ((r & 7) << 4)));
        unsigned short* dst = (l & 1) ? gbuf0 : gbuf1;
        st16_coh((char*)dst + (((size_t)(brow0 + r)) << 11) + memb * 128 + s * 16, v);
        if (even) {
          u32x4 v2 = *(const u32x4*)(smem + 4096 + r * 128 + ((s * 16) ^ ((r & 7) << 4)));
          unsigned short* z2dst = (e & 1) ? z2b0 : z2b1;
          st16_coh((char*)z2dst + (((size_t)(brow0 + r)) << 11) + memb * 128 + s * 16, v2);
        }
      }
    } else {
      // final step: f32 z1, scattered (runs once; epilogue reads it back)
#pragma unroll
      for (int i = 0; i < 4; ++i) {
        st_f32_coh(z1buf + (size_t)(brow0 + kq * 4 + i) * kH + hcol, z1n0[i]);
        st_f32_coh(z1buf + (size_t)(brow0 + 16 + kq * 4 + i) * kH + hcol, z1n1[i]);
      }
    }
    asm volatile("s_waitcnt vmcnt(0)" ::: "memory");
    __syncthreads();  // #2: all waves' exchange stores drained
    if (tid == 0) st_u32_coh(flags + grp * 16 + memb, (unsigned)(l + 1));

    // ---- E (odd): slack-issue z2[e] staging for next even step; no drain here ----
    if (!even && l + 1 < kL) stage_z2((e & 1) ? z2b0 : z2b1);

    // ---- D: X(l+2) -> Xbuf[l&1] (post-flag slack; normal cached loads) ----
    if (l + 2 < kL) {
      const int xr = tid >> 3, xq = tid & 7;
      const float* xp = X + (size_t)(brow0 + xr) * (kL * kI) + (size_t)(l + 2) * kI;
      fvec4 xv[8];
#pragma unroll
      for (int j = 0; j < 8; ++j) xv[j] = *(const fvec4*)(xp + xq * 4 + j * 32);
#pragma unroll
      for (int j = 0; j < 8; ++j) {
        int i0 = xq * 4 + j * 32;
        ushort4 pk;
        pk.x = f2bf(xv[j][0]); pk.y = f2bf(xv[j][1]);
        pk.z = f2bf(xv[j][2]); pk.w = f2bf(xv[j][3]);
        *(ushort4*)(smem + 131072 + ((l & 1) << 14) + (xr << 9) + ((i0 * 2) ^ ((xr & 7) << 4))) = pk;
      }
    }

    // ---- F: poll sibling flags for step l+1 (slack glls continue in flight) ----
    {
      const unsigned tgt = (unsigned)(l + 1);
      const unsigned* fp = flags + grp * 16 + (lane & 15);
      for (;;) {
        unsigned v = (lane < 16) ? ld_u32_coh(fp) : tgt;
        bool ok = (lane >= 16) || ((lane & 15) == memb) || (v >= tgt);
        if (__all(ok)) break;
        __builtin_amdgcn_s_sleep(1);
      }
      __builtin_amdgcn_sched_barrier(0);
    }
  }

  // ---- epilogue: out[b] = tanh(z1[b,:] . Wout + bout), one WG per group ----
  if (memb == 0) {
    int r = tid >> 3, q = tid & 7;
    const float* zr = z1buf + (size_t)(brow0 + r) * kH;
    float s = 0.f;
    for (int h = q * 128; h < q * 128 + 128; ++h) s += ld_f32_coh(zr + h) * Wout[h];
    s += __shfl_xor(s, 1);
    s += __shfl_xor(s, 2);
    s += __shfl_xor(s, 4);
    if (q == 0) out[brow0 + r] = tanh_fast(s + bout[0]);
  }
}

extern "C" void kernel_launch(void* const* d_in, const int* in_sizes, int n_in,
                              void* d_out, int out_size, void* d_ws, size_t ws_size,
                              hipStream_t stream) {
  const float* X = (const float*)d_in[0];
  const float* Win1 = (const float*)d_in[1];
  const float* bin1 = (const float*)d_in[2];
  const float* Wrec1 = (const float*)d_in[3];
  const float* Win2 = (const float*)d_in[4];
  const float* bin2 = (const float*)d_in[5];
  const float* Wrec2 = (const float*)d_in[6];
  const float* Wout = (const float*)d_in[7];
  const float* bout = (const float*)d_in[8];
  float* out = (float*)d_out;

  char* ws = (char*)d_ws;
  unsigned* flags = (unsigned*)ws;                                   // 256 dwords
  unsigned short* gbuf0 = (unsigned short*)(ws + 4096);              // 1 MB z12 ping
  unsigned short* gbuf1 = (unsigned short*)(ws + 4096 + (1 << 20));  // 1 MB z12 pong
  unsigned short* z2b0 = (unsigned short*)(ws + 4096 + (2 << 20));   // 1 MB z2 ping
  unsigned short* z2b1 = (unsigned short*)(ws + 4096 + (3 << 20));   // 1 MB z2 pong
  float* z1buf = (float*)(ws + 4096 + (4 << 20));                    // 2 MB final z1 (f32)

  (void)hipMemsetAsync(flags, 0, 4096, stream);
  (void)hipMemsetAsync(gbuf0, 0, (size_t)512 * 1024 * 2, stream);  // z12(l=0) = 0
  (void)hipMemsetAsync(z2b0, 0, (size_t)512 * 1024 * 2, stream);   // z2(l=0)  = 0

  (void)hipFuncSetAttribute((const void*)alarm_rnn_persist,
                            hipFuncAttributeMaxDynamicSharedMemorySize, 163840);

  alarm_rnn_persist<<<dim3(256), dim3(256), 163840, stream>>>(
      X, Win1, bin1, Wrec1, Win2, bin2, Wrec2, Wout, bout, out,
      flags, gbuf0, gbuf1, z2b0, z2b1, z1buf);
}

// Round 15
// 5173.328 us; speedup vs baseline: 1.4881x; 1.1988x over previous
//
#include <hip/hip_runtime.h>
#include <hip/hip_bf16.h>

typedef __attribute__((ext_vector_type(8))) short bhalf8;
typedef __attribute__((ext_vector_type(4))) float fvec4;
typedef __attribute__((ext_vector_type(4))) unsigned u32x4;

static __device__ __forceinline__ unsigned short f2bf(float f) {
  unsigned u = __builtin_bit_cast(unsigned, f);
  u = (u + 0x7fffu + ((u >> 16) & 1u)) >> 16;   // round-to-nearest-even
  return (unsigned short)u;
}
static __device__ __forceinline__ float tanh_fast(float x) {
  x = fminf(12.f, fmaxf(-12.f, x));
  float e = __expf(2.f * x);
  return (e - 1.f) / (e + 1.f);
}
static __device__ __forceinline__ fvec4 tanh4(fvec4 v) {
  fvec4 r;
  r[0] = tanh_fast(v[0]); r[1] = tanh_fast(v[1]);
  r[2] = tanh_fast(v[2]); r[3] = tanh_fast(v[3]);
  return r;
}
static __device__ __forceinline__ bhalf8 load_w8(const float* p) {
  fvec4 a = *(const fvec4*)p;
  fvec4 b = *(const fvec4*)(p + 4);
  bhalf8 r;
  r[0] = (short)f2bf(a[0]); r[1] = (short)f2bf(a[1]);
  r[2] = (short)f2bf(a[2]); r[3] = (short)f2bf(a[3]);
  r[4] = (short)f2bf(b[0]); r[5] = (short)f2bf(b[1]);
  r[6] = (short)f2bf(b[2]); r[7] = (short)f2bf(b[3]);
  return r;
}

// ---- fabric-coherent (sc0 sc1): the only proven tier (r4/r9/r12). SESSION RULES:
// ---- (1) no asm-load destination window across a GEMM (r6/r8) — glls are immune;
// ---- (2) staging via global_load_lds; (3) flags/polls fused-vmcnt sc0sc1;
// ---- (4) one poll/drain/flag per step (r13); (5) keep group staging synchronized —
// ---- spreading it breaks TCC multicast combining (r14).
static __device__ __forceinline__ void st_f32_coh(float* p, float v) {
  asm volatile("global_store_dword %0, %1, off sc0 sc1" :: "v"(p), "v"(v) : "memory");
}
static __device__ __forceinline__ void st_u32_coh(unsigned* p, unsigned v) {
  asm volatile("global_store_dword %0, %1, off sc0 sc1" :: "v"(p), "v"(v) : "memory");
}
static __device__ __forceinline__ void st16_coh(void* p, u32x4 v) {
  asm volatile("global_store_dwordx4 %0, %1, off sc0 sc1" :: "v"(p), "v"(v) : "memory");
}
static __device__ __forceinline__ unsigned ld_u32_coh(const unsigned* p) {
  unsigned v;
  asm volatile("global_load_dword %0, %1, off sc0 sc1\n\ts_waitcnt vmcnt(0)"
               : "=v"(v) : "v"(p) : "memory");
  return v;
}
static __device__ __forceinline__ float ld_f32_coh(const float* p) {
  float v;
  asm volatile("global_load_dword %0, %1, off sc0 sc1\n\ts_waitcnt vmcnt(0)"
               : "=v"(v) : "v"(p) : "memory");
  return v;
}
static __device__ __forceinline__ void gll16_coh(const void* g, void* lds) {
  __builtin_amdgcn_global_load_lds(
      (const __attribute__((address_space(1))) void*)g,
      (__attribute__((address_space(3))) void*)lds, 16, 0, 0x11);
}

#define MFMA16(a, b, c) __builtin_amdgcn_mfma_f32_16x16x32_bf16((a), (b), (c), 0, 0, 0)

// Persistent kernel, 256 WGs x 256 thr, 1 WG/CU -> grid HW-resident, spin safe.
// WG=(grp: 32 batch rows, memb: 64 H-cols). Round-12 protocol; GEMMs K-SPLIT across
// waves: wave w contracts K-quarter for ALL 4 n-tiles (A-fragments read once, not 4x)
// then partial accs are reduced through LDS. Cuts compute-phase LDS traffic ~4x.
extern "C" __global__ void __launch_bounds__(256, 1)
alarm_rnn_persist(const float* __restrict__ X, const float* __restrict__ Win1,
                  const float* __restrict__ bin1, const float* __restrict__ Wrec1,
                  const float* __restrict__ Win2, const float* __restrict__ bin2,
                  const float* __restrict__ Wrec2, const float* __restrict__ Wout,
                  const float* __restrict__ bout, float* __restrict__ out,
                  unsigned* flags, unsigned short* gbuf0, unsigned short* gbuf1,
                  unsigned short* z2b0, unsigned short* z2b1, float* z1buf)
{
  constexpr int kL = 512, kI = 256, kH = 1024;
  // LDS: [0,64K) z12 stage / acc-reduce scratch (z1 [0,32K), z2 [32K,64K))
  //      [64K,128K) z2 stage; [64K,72K) reused for transpose tiles post-GEMM
  //      [128K,160K) X ping-pong (2 x 16K)
  extern __shared__ char smem[];

  const int tid = threadIdx.x, bid = blockIdx.x;
  const int grp = bid >> 4, memb = bid & 15;
  const int lane = tid & 63, w = tid >> 6;
  const int row16 = lane & 15, kq = lane >> 4;
  const int sw = (row16 & 7) << 4;
  const int hcol = memb * 64 + w * 16 + row16;   // finalize/store col (n-tile = w)
  const int brow0 = grp * 32;

  // ---- weights, K-split layout: wave w holds K-quarter [w*256,+256) of Wrec* and
  // ---- [w*64,+64) of Win* for ALL 4 n-tiles of this member's 64 cols.
  bhalf8 w1[32], w2[32], wi1[8], wi2[8];
#pragma unroll
  for (int nt = 0; nt < 4; ++nt) {
    const size_t c = (size_t)(memb * 64 + nt * 16 + row16);
#pragma unroll
    for (int kk = 0; kk < 8; ++kk) {
      w1[nt * 8 + kk] = load_w8(Wrec1 + c * kH + w * 256 + kk * 32 + kq * 8);
      w2[nt * 8 + kk] = load_w8(Wrec2 + c * kH + w * 256 + kk * 32 + kq * 8);
    }
#pragma unroll
    for (int k2 = 0; k2 < 2; ++k2) {
      wi1[nt * 2 + k2] = load_w8(Win1 + c * kI + w * 64 + k2 * 32 + kq * 8);
      wi2[nt * 2 + k2] = load_w8(Win2 + c * kI + w * 64 + k2 * 32 + kq * 8);
    }
  }
  const float bv1 = bin1[hcol];
  const float bv2 = bin2[hcol];
  fvec4 z2c0 = {0.f, 0.f, 0.f, 0.f}, z2c1 = {0.f, 0.f, 0.f, 0.f};

  // ---- prologue: stage X(0) -> Xbuf0, X(1) -> Xbuf1 ----
  {
    int r = tid >> 3, q = tid & 7;
#pragma unroll
    for (int p = 0; p < 2; ++p) {
      const float* xp = X + (size_t)(brow0 + r) * (kL * kI) + (size_t)p * kI;
      fvec4 xv[8];
#pragma unroll
      for (int j = 0; j < 8; ++j) xv[j] = *(const fvec4*)(xp + q * 4 + j * 32);
#pragma unroll
      for (int j = 0; j < 8; ++j) {
        int i0 = q * 4 + j * 32;
        ushort4 pk;
        pk.x = f2bf(xv[j][0]); pk.y = f2bf(xv[j][1]);
        pk.z = f2bf(xv[j][2]); pk.w = f2bf(xv[j][3]);
        *(ushort4*)(smem + 131072 + p * 16384 + (r << 9) + ((i0 * 2) ^ ((r & 7) << 4))) = pk;
      }
    }
  }
  __syncthreads();

  for (int l = 0; l < kL; ++l) {
    const bool even = ((l & 1) == 0);
    const int e = l >> 1;

    // ---- A1: issue z12 (and z2 on even) global->LDS; member-staggered (r12) ----
    {
      const unsigned short* zsrc = (l & 1) ? gbuf1 : gbuf0;
#pragma unroll
      for (int it = 0; it < 16; ++it) {
        int itx = (it + memb) & 15;
        int c = ((itx * 4 + w) << 6) + lane;
        int r = c >> 7, cbs = (c & 127) * 16;
        gll16_coh((const char*)zsrc + (((size_t)(brow0 + r)) << 11) + (cbs ^ ((r & 7) << 4)),
                  smem + ((itx * 4 + w) << 10));
      }
      if (even) {
        const unsigned short* z2src = (e & 1) ? z2b1 : z2b0;
#pragma unroll
        for (int it = 0; it < 16; ++it) {
          int itx = (it + memb) & 15;
          int c = ((itx * 4 + w) << 6) + lane;
          int r = c >> 7, cbs = (c & 127) * 16;
          gll16_coh((const char*)z2src + (((size_t)(brow0 + r)) << 11) + (cbs ^ ((r & 7) << 4)),
                    smem + 65536 + ((itx * 4 + w) << 10));
        }
      }
      __builtin_amdgcn_sched_barrier(0);  // keep issues above the MFMA shadow
    }

    // ---- A2: Win*X partials (wave's K-quarter of 256) under the load shadow ----
    const char* xb = smem + 131072 + ((l & 1) << 14);
    fvec4 acc[8], c2a[8];
#pragma unroll
    for (int t = 0; t < 8; ++t) { acc[t] = {0.f, 0.f, 0.f, 0.f}; c2a[t] = {0.f, 0.f, 0.f, 0.f}; }
#pragma unroll
    for (int k2 = 0; k2 < 2; ++k2) {
      int cbx = (w * 2 + k2) * 64 + kq * 16;
      bhalf8 xa0 = *(const bhalf8*)(xb + (row16 << 9) + (cbx ^ sw));
      bhalf8 xa1 = *(const bhalf8*)(xb + ((16 + row16) << 9) + (cbx ^ sw));
#pragma unroll
      for (int nt = 0; nt < 4; ++nt) {
        acc[nt * 2] = MFMA16(xa0, wi1[nt * 2 + k2], acc[nt * 2]);
        acc[nt * 2 + 1] = MFMA16(xa1, wi1[nt * 2 + k2], acc[nt * 2 + 1]);
      }
      if (even) {
#pragma unroll
        for (int nt = 0; nt < 4; ++nt) {
          c2a[nt * 2] = MFMA16(xa0, wi2[nt * 2 + k2], c2a[nt * 2]);
          c2a[nt * 2 + 1] = MFMA16(xa1, wi2[nt * 2 + k2], c2a[nt * 2 + 1]);
        }
      }
    }
    // ---- A3: staged data complete -> visible to all waves ----
    asm volatile("s_waitcnt vmcnt(0)" ::: "memory");
    __builtin_amdgcn_sched_barrier(0);
    __syncthreads();  // #1

    // ---- B1: Wrec1*z12 partial (wave's K-quarter; A-fragments read ONCE) ----
#pragma unroll
    for (int kk = 0; kk < 8; ++kk) {
      int cb = (w * 8 + kk) * 64 + kq * 16;
      bhalf8 a0 = *(const bhalf8*)(smem + (row16 << 11) + (cb ^ sw));
      bhalf8 a1 = *(const bhalf8*)(smem + ((16 + row16) << 11) + (cb ^ sw));
#pragma unroll
      for (int nt = 0; nt < 4; ++nt) {
        acc[nt * 2] = MFMA16(a0, w1[nt * 8 + kk], acc[nt * 2]);
        acc[nt * 2 + 1] = MFMA16(a1, w1[nt * 8 + kk], acc[nt * 2 + 1]);
      }
    }
    // ---- B2 (even): Wrec2*z2 partial ----
    if (even) {
#pragma unroll
      for (int kk = 0; kk < 8; ++kk) {
        int cb = (w * 8 + kk) * 64 + kq * 16;
        bhalf8 a0 = *(const bhalf8*)(smem + 65536 + (row16 << 11) + (cb ^ sw));
        bhalf8 a1 = *(const bhalf8*)(smem + 65536 + ((16 + row16) << 11) + (cb ^ sw));
#pragma unroll
        for (int nt = 0; nt < 4; ++nt) {
          c2a[nt * 2] = MFMA16(a0, w2[nt * 8 + kk], c2a[nt * 2]);
          c2a[nt * 2 + 1] = MFMA16(a1, w2[nt * 8 + kk], c2a[nt * 2 + 1]);
        }
      }
    }

    // ---- R1: write partial accs to LDS reduce buffers ----
    __syncthreads();  // #2: all GEMM reads of z12/z2 LDS done -> regions reusable
#pragma unroll
    for (int nt = 0; nt < 4; ++nt)
#pragma unroll
      for (int mt = 0; mt < 2; ++mt) {
        int base = (((nt * 2 + mt) * 4 + w) << 10);
        fvec4 v = acc[nt * 2 + mt];
#pragma unroll
        for (int i = 0; i < 4; ++i)
          *(float*)(smem + base + (((kq * 4 + i) * 16 + row16) << 2)) = v[i];
        if (even) {
          fvec4 v2 = c2a[nt * 2 + mt];
#pragma unroll
          for (int i = 0; i < 4; ++i)
            *(float*)(smem + 32768 + base + (((kq * 4 + i) * 16 + row16) << 2)) = v2[i];
        }
      }
    __syncthreads();  // #3: partials visible

    // ---- R2: finalize own n-tile (nt = w): sum 4 partials + bias -> tanh ----
    fvec4 s0 = {0.f, 0.f, 0.f, 0.f}, s1 = s0;
#pragma unroll
    for (int ws = 0; ws < 4; ++ws) {
      int b0 = (((w * 2 + 0) * 4 + ws) << 10), b1 = (((w * 2 + 1) * 4 + ws) << 10);
#pragma unroll
      for (int i = 0; i < 4; ++i) {
        s0[i] += *(const float*)(smem + b0 + (((kq * 4 + i) * 16 + row16) << 2));
        s1[i] += *(const float*)(smem + b1 + (((kq * 4 + i) * 16 + row16) << 2));
      }
    }
#pragma unroll
    for (int i = 0; i < 4; ++i) { s0[i] += bv1; s1[i] += bv1; }
    fvec4 z1n0 = tanh4(s0), z1n1 = tanh4(s1);
    if (even) {
      fvec4 t0 = {0.f, 0.f, 0.f, 0.f}, t1 = t0;
#pragma unroll
      for (int ws = 0; ws < 4; ++ws) {
        int b0 = 32768 + (((w * 2 + 0) * 4 + ws) << 10), b1 = 32768 + (((w * 2 + 1) * 4 + ws) << 10);
#pragma unroll
        for (int i = 0; i < 4; ++i) {
          t0[i] += *(const float*)(smem + b0 + (((kq * 4 + i) * 16 + row16) << 2));
          t1[i] += *(const float*)(smem + b1 + (((kq * 4 + i) * 16 + row16) << 2));
        }
      }
#pragma unroll
      for (int i = 0; i < 4; ++i) { t0[i] += bv2; t1[i] += bv2; }
      z2c0 = tanh4(t0);
      z2c1 = tanh4(t1);
    }

    // ---- C: coalesced publish via transpose tiles in z2-stage region (idle now) ----
    if (l < kL - 1) {
      const int colb = (w * 16 + row16) * 2;  // byte col within this WG's 64-col tile
#pragma unroll
      for (int i = 0; i < 4; ++i) {
        int r0 = kq * 4 + i, r1 = 16 + kq * 4 + i;
        *(unsigned short*)(smem + 65536 + r0 * 128 + (colb ^ ((r0 & 7) << 4))) = f2bf(z1n0[i] + z2c0[i]);
        *(unsigned short*)(smem + 65536 + r1 * 128 + (colb ^ ((r1 & 7) << 4))) = f2bf(z1n1[i] + z2c1[i]);
      }
      if (even) {
#pragma unroll
        for (int i = 0; i < 4; ++i) {
          int r0 = kq * 4 + i, r1 = 16 + kq * 4 + i;
          *(unsigned short*)(smem + 69632 + r0 * 128 + (colb ^ ((r0 & 7) << 4))) = f2bf(z2c0[i]);
          *(unsigned short*)(smem + 69632 + r1 * 128 + (colb ^ ((r1 & 7) << 4))) = f2bf(z2c1[i]);
        }
      }
      __syncthreads();  // #4: transpose tiles complete
      {
        int r = tid >> 3, s = tid & 7;
        u32x4 v = *(const u32x4*)(smem + 65536 + r * 128 + ((s * 16) ^ ((r & 7) << 4)));
        unsigned short* dst = (l & 1) ? gbuf0 : gbuf1;
        st16_coh((char*)dst + (((size_t)(brow0 + r)) << 11) + memb * 128 + s * 16, v);
        if (even) {
          u32x4 v2 = *(const u32x4*)(smem + 69632 + r * 128 + ((s * 16) ^ ((r & 7) << 4)));
          unsigned short* z2dst = (e & 1) ? z2b0 : z2b1;
          st16_coh((char*)z2dst + (((size_t)(brow0 + r)) << 11) + memb * 128 + s * 16, v2);
        }
      }
    } else {
      // final step: f32 z1, scattered (runs once; epilogue reads it back)
#pragma unroll
      for (int i = 0; i < 4; ++i) {
        st_f32_coh(z1buf + (size_t)(brow0 + kq * 4 + i) * kH + hcol, z1n0[i]);
        st_f32_coh(z1buf + (size_t)(brow0 + 16 + kq * 4 + i) * kH + hcol, z1n1[i]);
      }
    }
    asm volatile("s_waitcnt vmcnt(0)" ::: "memory");
    __syncthreads();  // #5: all waves' exchange stores drained
    if (tid == 0) st_u32_coh(flags + grp * 16 + memb, (unsigned)(l + 1));

    // ---- D: X(l+2) -> Xbuf[l&1] (post-flag slack; normal cached loads) ----
    if (l + 2 < kL) {
      const int xr = tid >> 3, xq = tid & 7;
      const float* xp = X + (size_t)(brow0 + xr) * (kL * kI) + (size_t)(l + 2) * kI;
      fvec4 xv[8];
#pragma unroll
      for (int j = 0; j < 8; ++j) xv[j] = *(const fvec4*)(xp + xq * 4 + j * 32);
#pragma unroll
      for (int j = 0; j < 8; ++j) {
        int i0 = xq * 4 + j * 32;
        ushort4 pk;
        pk.x = f2bf(xv[j][0]); pk.y = f2bf(xv[j][1]);
        pk.z = f2bf(xv[j][2]); pk.w = f2bf(xv[j][3]);
        *(ushort4*)(smem + 131072 + ((l & 1) << 14) + (xr << 9) + ((i0 * 2) ^ ((xr & 7) << 4))) = pk;
      }
    }

    // ---- F: poll sibling flags for step l+1 ----
    {
      const unsigned tgt = (unsigned)(l + 1);
      const unsigned* fp = flags + grp * 16 + (lane & 15);
      for (;;) {
        unsigned v = (lane < 16) ? ld_u32_coh(fp) : tgt;
        bool ok = (lane >= 16) || ((lane & 15) == memb) || (v >= tgt);
        if (__all(ok)) break;
        __builtin_amdgcn_s_sleep(1);
      }
      __builtin_amdgcn_sched_barrier(0);
    }
  }

  // ---- epilogue: out[b] = tanh(z1[b,:] . Wout + bout), one WG per group ----
  if (memb == 0) {
    int r = tid >> 3, q = tid & 7;
    const float* zr = z1buf + (size_t)(brow0 + r) * kH;
    float s = 0.f;
    for (int h = q * 128; h < q * 128 + 128; ++h) s += ld_f32_coh(zr + h) * Wout[h];
    s += __shfl_xor(s, 1);
    s += __shfl_xor(s, 2);
    s += __shfl_xor(s, 4);
    if (q == 0) out[brow0 + r] = tanh_fast(s + bout[0]);
  }
}

extern "C" void kernel_launch(void* const* d_in, const int* in_sizes, int n_in,
                              void* d_out, int out_size, void* d_ws, size_t ws_size,
                              hipStream_t stream) {
  const float* X = (const float*)d_in[0];
  const float* Win1 = (const float*)d_in[1];
  const float* bin1 = (const float*)d_in[2];
  const float* Wrec1 = (const float*)d_in[3];
  const float* Win2 = (const float*)d_in[4];
  const float* bin2 = (const float*)d_in[5];
  const float* Wrec2 = (const float*)d_in[6];
  const float* Wout = (const float*)d_in[7];
  const float* bout = (const float*)d_in[8];
  float* out = (float*)d_out;

  char* ws = (char*)d_ws;
  unsigned* flags = (unsigned*)ws;                                   // 256 dwords
  unsigned short* gbuf0 = (unsigned short*)(ws + 4096);              // 1 MB z12 ping
  unsigned short* gbuf1 = (unsigned short*)(ws + 4096 + (1 << 20));  // 1 MB z12 pong
  unsigned short* z2b0 = (unsigned short*)(ws + 4096 + (2 << 20));   // 1 MB z2 ping
  unsigned short* z2b1 = (unsigned short*)(ws + 4096 + (3 << 20));   // 1 MB z2 pong
  float* z1buf = (float*)(ws + 4096 + (4 << 20));                    // 2 MB final z1 (f32)

  (void)hipMemsetAsync(flags, 0, 4096, stream);
  (void)hipMemsetAsync(gbuf0, 0, (size_t)512 * 1024 * 2, stream);  // z12(l=0) = 0
  (void)hipMemsetAsync(z2b0, 0, (size_t)512 * 1024 * 2, stream);   // z2(l=0)  = 0

  (void)hipFuncSetAttribute((const void*)alarm_rnn_persist,
                            hipFuncAttributeMaxDynamicSharedMemorySize, 163840);

  alarm_rnn_persist<<<dim3(256), dim3(256), 163840, stream>>>(
      X, Win1, bin1, Wrec1, Win2, bin2, Wrec2, Wout, bout, out,
      flags, gbuf0, gbuf1, z2b0, z2b1, z1buf);
}